// Round 15
// baseline (327.568 us; speedup 1.0000x reference)
//
#include <hip/hip_runtime.h>
#include <hip/hip_fp16.h>
#include <hip/hip_cooperative_groups.h>
#include <cstdint>
#include <cstddef>

namespace cg = cooperative_groups;

// ---------------------------------------------------------------------------
// GCN 2-layer: out = GCNConv2( relu( GCNConv1(x) ) )
// Build — ONE cooperative kernel (k_build), zero global atomics:
//   phase A : per-chunk LDS histogram over 256-node buckets -> histM;
//             decoded (src,dst) cached in LDS for phase D
//   phase B : per-bucket scan over chunks -> within-bucket chunk offsets
//   phase C : (block 0) scan bucket totals -> bbase[]; zero-rows of h1/h2
//   phase D : direct scatter from the LDS edge cache -> bucket-grouped raw[]
//   phase E : per-bucket node histogram + scan -> rowptr/dinv + LDS counting
//             sort -> per-node CSR rec[]
// Compute:
//   k_gemm    : Hs1(fp16) = (X @ W1) * dinv[row]
//   k_prop64f : FUSED layer-1 prop + layer-2 transform (g1 in regs/LDS,
//               matvec epilogue) -> h2(fp16) = (g1 @ W2) * dinv
//   k_prop32  : out[n] = dinv[n]*(sum h2[src] + h2[n]) + b2  (fp32 out)
// Edge dtype (int32 vs int64) detected per-block via wave-0 ballot on the
// odd 32-bit words of the first 64 edges (int64 node ids < 2^31 -> all 0).
// ---------------------------------------------------------------------------

#define CHUNK 4096      // edges per partition block
#define BKN 256         // nodes per bucket
#define BKN_SHIFT 8
#define NCH_MAX 512     // max chunks / max buckets
#define SCAP2 5120      // LDS cap per bucket in sort (mean 4096, +16 sigma)

__device__ __forceinline__ int load_edge(const int* e32, int idx, int is64) {
  if (is64) return (int)((const long long*)e32)[idx];
  return e32[idx];
}

// inclusive Hillis-Steele over 512 LDS slots with 256 threads
__device__ __forceinline__ void block_scan512(int* sh, int t) {
  for (int off = 1; off < 512; off <<= 1) {
    int i0 = t, i1 = t + 256;
    int v0 = sh[i0] + ((i0 >= off) ? sh[i0 - off] : 0);
    int v1 = sh[i1] + ((i1 >= off) ? sh[i1 - off] : 0);
    __syncthreads();
    sh[i0] = v0;
    sh[i1] = v1;
    __syncthreads();
  }
}

// ---- cooperative build: hist -> colscan -> bscan -> scatter -> sort ----
__global__ void k_build(const int* __restrict__ e32, int E, int* __restrict__ histM,
                        int* __restrict__ btot, int* __restrict__ bbase,
                        int* __restrict__ rowptr, float* __restrict__ dinv,
                        unsigned int* __restrict__ raw, int* __restrict__ rec,
                        __half* __restrict__ h1, __half* __restrict__ h2,
                        int NCH, int NBUCK, int N) {
  cg::grid_group grid = cg::this_grid();
  __shared__ int s_flag;
  __shared__ char smem[34816];
  int* cacheD = (int*)smem;                 // 16 KB (phases A,D)
  int* cacheS = (int*)(smem + 16384);       // 16 KB (phases A,D)
  int* aux    = (int*)(smem + 32768);       // 2 KB: lh / scan sh / cursors
  int* srec   = (int*)smem;                 // 20 KB (phase E, overlays cache)
  int* shE    = (int*)(smem + 20480);       // 1 KB  (phase E)

  const int t = threadIdx.x;
  const int c = blockIdx.x;                 // chunk id (phases A,D)
  const int b = blockIdx.x;                 // bucket id (phases B,E)

  // dtype detect (per block)
  if (t < 64) {
    int v = e32[2 * t + 1];
    unsigned long long bl = __ballot(v != 0);
    if (t == 0) s_flag = (bl == 0ULL);
  }
  __syncthreads();
  const int is64 = s_flag;

  const int beg = c * CHUNK;
  const int cnt = (c < NCH) ? min(CHUNK, E - beg) : 0;

  // ---- phase A: decode+cache edges, LDS bucket histogram -> histM ----
  if (c < NCH) {
    for (int i = t; i < NBUCK; i += 256) aux[i] = 0;
    __syncthreads();
    for (int i = t; i < cnt; i += 256) {
      int s = load_edge(e32, beg + i, is64);
      int d = load_edge(e32, E + beg + i, is64);
      cacheS[i] = s;
      cacheD[i] = d;
      atomicAdd(&aux[d >> BKN_SHIFT], 1);   // LDS atomic: on-CU, cheap
    }
    __syncthreads();
    for (int i = t; i < NBUCK; i += 256) histM[(size_t)c * NBUCK + i] = aux[i];
  }
  grid.sync();

  // ---- phase B: per-bucket scan over chunks (aux as sh[512]) ----
  if (b < NBUCK) {
    for (int i = t; i < NCH_MAX; i += 256)
      aux[i] = (i < NCH) ? histM[(size_t)i * NBUCK + b] : 0;
    __syncthreads();
    block_scan512(aux, t);  // inclusive
    for (int i = t; i < NCH; i += 256)
      histM[(size_t)i * NBUCK + b] = (i == 0) ? 0 : aux[i - 1];  // exclusive
    if (t == 0) btot[b] = aux[NCH_MAX - 1];
  }
  grid.sync();

  // ---- phase C: block 0 scans bucket totals -> bbase; zero-rows ----
  if (blockIdx.x == 0) {
    aux[t] = (t < NBUCK) ? btot[t] : 0;
    aux[t + 256] = (t + 256 < NBUCK) ? btot[t + 256] : 0;
    __syncthreads();
    block_scan512(aux, t);  // inclusive
    for (int i = t; i < NBUCK; i += 256) bbase[i] = (i == 0) ? 0 : aux[i - 1];
    if (t == 0) { bbase[NBUCK] = E; rowptr[N] = E; }
    if (t < 64) {
      h1[(size_t)N * 64 + t] = __float2half(0.f);   // zero-row (gather target)
      if (t < 32) h2[(size_t)N * 32 + t] = __float2half(0.f);
    }
  }
  grid.sync();

  // ---- phase D: scatter from LDS cache via LDS cursors -> raw ----
  if (c < NCH) {
    for (int i = t; i < NBUCK; i += 256)
      aux[i] = histM[(size_t)c * NBUCK + i] + bbase[i];
    __syncthreads();
    for (int i = t; i < cnt; i += 256) {
      int s = cacheS[i];
      int d = cacheD[i];
      int pos = atomicAdd(&aux[d >> BKN_SHIFT], 1);
      raw[pos] = ((unsigned int)(d & (BKN - 1)) << 23) | (unsigned int)s;
    }
  }
  grid.sync();

  // ---- phase E: per-bucket node hist + scan -> rowptr/dinv; counting sort ----
  if (b < NBUCK) {
    const int nodebase = b << BKN_SHIFT;
    const int base = bbase[b];
    const int end = bbase[b + 1];
    const int count = end - base;
    shE[t] = 0;
    __syncthreads();
    for (int i = t; i < count; i += 256) atomicAdd(&shE[raw[base + i] >> 23], 1);
    __syncthreads();
    const int deg = shE[t];  // in-degree of node nodebase+t
    for (int off = 1; off < 256; off <<= 1) {
      int add = (t >= off) ? shE[t - off] : 0;
      __syncthreads();
      shE[t] += add;
      __syncthreads();
    }
    const int excl = shE[t] - deg;
    const int n = nodebase + t;
    if (n < N) {
      rowptr[n] = base + excl;                   // coalesced, atomic-free
      dinv[n] = rsqrtf((float)deg + 1.0f);       // +1 = self-loop
    }
    __syncthreads();
    shE[t] = excl;  // local cursors
    __syncthreads();
    if (count <= SCAP2) {
      for (int i = t; i < count; i += 256) {
        unsigned int r = raw[base + i];
        int pos = atomicAdd(&shE[r >> 23], 1);
        srec[pos] = (int)(r & 0x7FFFFFu);
      }
      __syncthreads();
      for (int i = t; i < count; i += 256) rec[base + i] = srec[i];
    } else {  // statistically unreachable fallback: direct global placement
      for (int i = t; i < count; i += 256) {
        unsigned int r = raw[base + i];
        int pos = atomicAdd(&shE[r >> 23], 1);
        rec[base + pos] = (int)(r & 0x7FFFFFu);
      }
    }
  }
}

// ---- dense transform Hs[N][COUT] = (X[N][CIN] @ W) * dinv[row], fp16 out ----
template <int CIN, int COUT>
__global__ void k_gemm(const float* __restrict__ Xv, const float* __restrict__ W,
                       const float* __restrict__ dinv, __half* __restrict__ H, int N) {
  constexpr int Q = COUT / 4;
  constexpr int NODES = 256 / Q;
  __shared__ float4 Ws[CIN * Q];
  __shared__ float Xs[NODES][CIN + 1];
  const int t = threadIdx.x;
  const int nodebase = blockIdx.x * NODES;

  const float4* W4 = (const float4*)W;
#pragma unroll
  for (int i = t; i < CIN * Q; i += 256) Ws[i] = W4[i];

  const float4* X4 = (const float4*)Xv;
#pragma unroll
  for (int i = t; i < NODES * (CIN / 4); i += 256) {
    int r = i / (CIN / 4);
    int k4 = i % (CIN / 4);
    int gr = nodebase + r;
    if (gr > N - 1) gr = N - 1;
    float4 v = X4[(size_t)gr * (CIN / 4) + k4];
    Xs[r][k4 * 4 + 0] = v.x;
    Xs[r][k4 * 4 + 1] = v.y;
    Xs[r][k4 * 4 + 2] = v.z;
    Xs[r][k4 * 4 + 3] = v.w;
  }
  __syncthreads();

  const int q = t % Q;
  const int nl = t / Q;
  const int n = nodebase + nl;
  float4 acc = make_float4(0.f, 0.f, 0.f, 0.f);
#pragma unroll 4
  for (int k = 0; k < CIN; ++k) {
    float xv = Xs[nl][k];
    float4 wv = Ws[k * Q + q];
    acc.x = fmaf(xv, wv.x, acc.x);
    acc.y = fmaf(xv, wv.y, acc.y);
    acc.z = fmaf(xv, wv.z, acc.z);
    acc.w = fmaf(xv, wv.w, acc.w);
  }
  if (n < N) {
    float dn = dinv[n];  // fold symmetric norm into stored features
    __half2* H2 = (__half2*)H;
    H2[(size_t)n * (COUT / 2) + 2 * q + 0] = __floats2half2_rn(acc.x * dn, acc.y * dn);
    H2[(size_t)n * (COUT / 2) + 2 * q + 1] = __floats2half2_rn(acc.z * dn, acc.w * dn);
  }
}

// accumulate a float4 (= 8 fp16 channels) into 4 f32 float2 accumulators
__device__ __forceinline__ void acc_row(float4 hv, float2& a0, float2& a1,
                                        float2& a2, float2& a3) {
  union { float f; __half2 h; } c0, c1, c2, c3;
  c0.f = hv.x; c1.f = hv.y; c2.f = hv.z; c3.f = hv.w;
  float2 f0 = __half22float2(c0.h), f1 = __half22float2(c1.h);
  float2 f2 = __half22float2(c2.h), f3 = __half22float2(c3.h);
  a0.x += f0.x; a0.y += f0.y;
  a1.x += f1.x; a1.y += f1.y;
  a2.x += f2.x; a2.y += f2.y;
  a3.x += f3.x; a3.y += f3.y;
}

#define RED2(v, m) { v.x += __shfl_xor(v.x, m); v.y += __shfl_xor(v.y, m); }

// ---- FUSED layer-1 prop + layer-2 transform ----
// 4 nodes/wave, 2 groups x 8 lanes, unroll-8 stride-16 gather loop (MLP-8).
// Epilogue: g1 row (relu'd, f32) -> per-wave LDS; 16-lane matvec with W2
// pairs (broadcast LDS reads); h2[n] = (g1row @ W2) * dinv[n], fp16.
__global__ void k_prop64f(const __half2* __restrict__ H2, const int* __restrict__ rec,
                          const int* __restrict__ rowptr, const float* __restrict__ dinv,
                          const float* __restrict__ b1, const float* __restrict__ W2,
                          __half* __restrict__ h2, int N) {
  __shared__ float2 W2p[64 * 16];        // W2p[c][k] = (W2[c][k], W2[c][k+16])
  __shared__ float g1buf[4][4][68];      // [wave][node][64ch + pad]
  const int t = threadIdx.x;
  const int lane = t & 63;
  const int wave = t >> 6;
  // stage paired W2 (8 KB)
  for (int i = t; i < 64 * 16; i += 256) {
    int c = i >> 4, k = i & 15;
    W2p[i] = make_float2(W2[c * 32 + k], W2[c * 32 + 16 + k]);
  }

  const int nl = lane >> 4;                       // node within wave 0..3
  int n = blockIdx.x * 16 + wave * 4 + nl;
  if (n > N - 1) n = N - 1;                       // clamp (dup compute, benign)
  const int g = (lane & 15) >> 3;                 // edge group 0..1
  const int l8 = lane & 7;                        // float4 index (8 channels)
  const float di = dinv[n];
  const int beg = rowptr[n];
  const int end = rowptr[n + 1];
  const float4* H4 = (const float4*)H2;
  float2 a0 = {0.f, 0.f}, a1 = {0.f, 0.f}, a2 = {0.f, 0.f}, a3 = {0.f, 0.f};
  acc_row(H4[(size_t)(g == 0 ? n : N) * 8 + l8], a0, a1, a2, a3);  // self-loop
  for (int e = beg + g; e < end; e += 16) {
    // slot 0 guaranteed by loop condition; slots 1-7 gather zero-row on tail
    int s0 = rec[e];
    int s1 = (e + 2  < end) ? rec[e + 2]  : N;   // rec has +64 slack
    int s2 = (e + 4  < end) ? rec[e + 4]  : N;
    int s3 = (e + 6  < end) ? rec[e + 6]  : N;
    int s4 = (e + 8  < end) ? rec[e + 8]  : N;
    int s5 = (e + 10 < end) ? rec[e + 10] : N;
    int s6 = (e + 12 < end) ? rec[e + 12] : N;
    int s7 = (e + 14 < end) ? rec[e + 14] : N;
    acc_row(H4[(size_t)s0 * 8 + l8], a0, a1, a2, a3);
    acc_row(H4[(size_t)s1 * 8 + l8], a0, a1, a2, a3);
    acc_row(H4[(size_t)s2 * 8 + l8], a0, a1, a2, a3);
    acc_row(H4[(size_t)s3 * 8 + l8], a0, a1, a2, a3);
    acc_row(H4[(size_t)s4 * 8 + l8], a0, a1, a2, a3);
    acc_row(H4[(size_t)s5 * 8 + l8], a0, a1, a2, a3);
    acc_row(H4[(size_t)s6 * 8 + l8], a0, a1, a2, a3);
    acc_row(H4[(size_t)s7 * 8 + l8], a0, a1, a2, a3);
  }
  // combine the 2 groups (mask stays within the 16-lane span = one node);
  // after this BOTH groups hold the full sums.
  RED2(a0, 8)  RED2(a1, 8)  RED2(a2, 8)  RED2(a3, 8)

  // g1 row values: relu(a*di + b1), channels 8*l8..8*l8+7
  const float4* B4 = (const float4*)b1;
  float4 bb0 = B4[l8 * 2 + 0], bb1 = B4[l8 * 2 + 1];
  if (g == 0) {
    float4 r0 = make_float4(fmaxf(fmaf(a0.x, di, bb0.x), 0.f),
                            fmaxf(fmaf(a0.y, di, bb0.y), 0.f),
                            fmaxf(fmaf(a1.x, di, bb0.z), 0.f),
                            fmaxf(fmaf(a1.y, di, bb0.w), 0.f));
    float4 r1 = make_float4(fmaxf(fmaf(a2.x, di, bb1.x), 0.f),
                            fmaxf(fmaf(a2.y, di, bb1.y), 0.f),
                            fmaxf(fmaf(a3.x, di, bb1.z), 0.f),
                            fmaxf(fmaf(a3.y, di, bb1.w), 0.f));
    *(float4*)&g1buf[wave][nl][l8 * 8 + 0] = r0;
    *(float4*)&g1buf[wave][nl][l8 * 8 + 4] = r1;
  }
  __syncthreads();  // W2p staged AND g1buf written (all threads reach)

  // matvec: lane k in node span computes outputs k and k+16
  const int k = lane & 15;
  float o0 = 0.f, o1 = 0.f;
#pragma unroll
  for (int c4 = 0; c4 < 16; ++c4) {
    float4 r = *(const float4*)&g1buf[wave][nl][c4 * 4];  // broadcast read
    float2 w0 = W2p[(c4 * 4 + 0) * 16 + k];               // broadcast read
    float2 w1 = W2p[(c4 * 4 + 1) * 16 + k];
    float2 w2 = W2p[(c4 * 4 + 2) * 16 + k];
    float2 w3 = W2p[(c4 * 4 + 3) * 16 + k];
    o0 = fmaf(r.x, w0.x, o0); o1 = fmaf(r.x, w0.y, o1);
    o0 = fmaf(r.y, w1.x, o0); o1 = fmaf(r.y, w1.y, o1);
    o0 = fmaf(r.z, w2.x, o0); o1 = fmaf(r.z, w2.y, o1);
    o0 = fmaf(r.w, w3.x, o0); o1 = fmaf(r.w, w3.y, o1);
  }
  // h2[n][c'] = (g1 @ W2)[c'] * dinv[n]   (bias2 added in k_prop32)
  h2[(size_t)n * 32 + k]      = __float2half(o0 * di);
  h2[(size_t)n * 32 + k + 16] = __float2half(o1 * di);
}

// ---- pull prop C=32: 8 nodes/wave, 2 groups x 4 lanes, unroll-8 stride-16 ----
__global__ void k_prop32(const __half2* __restrict__ H2, const int* __restrict__ rec,
                         const int* __restrict__ rowptr, const float* __restrict__ dinv,
                         const float* __restrict__ bias, float* __restrict__ out, int N) {
  const int lane = threadIdx.x & 63;
  const int wave = threadIdx.x >> 6;
  const int n = blockIdx.x * 32 + wave * 8 + (lane >> 3);  // 32 nodes per block
  if (n >= N) return;
  const int g = (lane & 7) >> 2;   // edge group 0..1 within the 8-lane span
  const int l4 = lane & 3;         // float4 index within row (8 channels)
  const float di = dinv[n];
  const int beg = rowptr[n];
  const int end = rowptr[n + 1];
  const float4* H4 = (const float4*)H2;
  float2 a0 = {0.f, 0.f}, a1 = {0.f, 0.f}, a2 = {0.f, 0.f}, a3 = {0.f, 0.f};
  acc_row(H4[(size_t)(g == 0 ? n : N) * 4 + l4], a0, a1, a2, a3);  // self-loop
  for (int e = beg + g; e < end; e += 16) {
    int s0 = rec[e];
    int s1 = (e + 2  < end) ? rec[e + 2]  : N;
    int s2 = (e + 4  < end) ? rec[e + 4]  : N;
    int s3 = (e + 6  < end) ? rec[e + 6]  : N;
    int s4 = (e + 8  < end) ? rec[e + 8]  : N;
    int s5 = (e + 10 < end) ? rec[e + 10] : N;
    int s6 = (e + 12 < end) ? rec[e + 12] : N;
    int s7 = (e + 14 < end) ? rec[e + 14] : N;
    acc_row(H4[(size_t)s0 * 4 + l4], a0, a1, a2, a3);
    acc_row(H4[(size_t)s1 * 4 + l4], a0, a1, a2, a3);
    acc_row(H4[(size_t)s2 * 4 + l4], a0, a1, a2, a3);
    acc_row(H4[(size_t)s3 * 4 + l4], a0, a1, a2, a3);
    acc_row(H4[(size_t)s4 * 4 + l4], a0, a1, a2, a3);
    acc_row(H4[(size_t)s5 * 4 + l4], a0, a1, a2, a3);
    acc_row(H4[(size_t)s6 * 4 + l4], a0, a1, a2, a3);
    acc_row(H4[(size_t)s7 * 4 + l4], a0, a1, a2, a3);
  }
  // combine the 2 groups (mask stays within the 8-lane span = one node)
  RED2(a0, 4)  RED2(a1, 4)  RED2(a2, 4)  RED2(a3, 4)
  if (g) return;
  const float4* B4 = (const float4*)bias;
  float4 b0 = B4[l4 * 2 + 0], b1 = B4[l4 * 2 + 1];
  ((float4*)out)[(size_t)n * 8 + l4 * 2 + 0] =
      make_float4(fmaf(a0.x, di, b0.x), fmaf(a0.y, di, b0.y),
                  fmaf(a1.x, di, b0.z), fmaf(a1.y, di, b0.w));
  ((float4*)out)[(size_t)n * 8 + l4 * 2 + 1] =
      make_float4(fmaf(a2.x, di, b1.x), fmaf(a2.y, di, b1.y),
                  fmaf(a3.x, di, b1.z), fmaf(a3.y, di, b1.w));
}

extern "C" void kernel_launch(void* const* d_in, const int* in_sizes, int n_in,
                              void* d_out, int out_size, void* d_ws, size_t ws_size,
                              hipStream_t stream) {
  (void)n_in; (void)out_size; (void)ws_size;
  const float* x = (const float*)d_in[0];
  const int* edges = (const int*)d_in[1];
  const float* W1 = (const float*)d_in[2];
  const float* b1 = (const float*)d_in[3];
  const float* W2 = (const float*)d_in[4];
  const float* b2 = (const float*)d_in[5];

  const int N = in_sizes[0] / 64;
  const int E = in_sizes[1] / 2;
  const int NCH = (E + CHUNK - 1) / CHUNK;        // 391 (<= 512)
  const int NBUCK = (N + BKN - 1) / BKN;          // 391 (<= 512)
  const int GRID = (NCH > NBUCK) ? NCH : NBUCK;

  // workspace carve-up (256B aligned)
  char* ws = (char*)d_ws;
  size_t off = 0;
  auto carve = [&](size_t bytes) -> void* {
    void* p = ws + off;
    off = (off + bytes + 255) & ~(size_t)255;
    return p;
  };
  int* rowptr        = (int*)carve((size_t)(N + 1) * 4);
  float* dinv        = (float*)carve((size_t)N * 4);
  int* btot          = (int*)carve((size_t)NBUCK * 4);
  int* bbase         = (int*)carve((size_t)(NBUCK + 1) * 4);
  int* histM         = (int*)carve((size_t)NCH * NBUCK * 4);
  unsigned int* raw  = (unsigned int*)carve((size_t)E * 4);
  int* rec           = (int*)carve(((size_t)E + 64) * 4);   // +slack for over-read
  __half* h1         = (__half*)carve((size_t)(N + 1) * 64 * 2);  // +zero-row
  __half* h2         = (__half*)carve((size_t)(N + 1) * 32 * 2);

  // cooperative build: hist -> colscan -> bscan -> scatter -> sort
  {
    int E_ = E, NCH_ = NCH, NBUCK_ = NBUCK, N_ = N;
    const int* e_ = edges;
    void* args[] = {(void*)&e_,     (void*)&E_,    (void*)&histM, (void*)&btot,
                    (void*)&bbase,  (void*)&rowptr,(void*)&dinv,  (void*)&raw,
                    (void*)&rec,    (void*)&h1,    (void*)&h2,    (void*)&NCH_,
                    (void*)&NBUCK_, (void*)&N_};
    hipLaunchCooperativeKernel((const void*)k_build, dim3(GRID), dim3(256),
                               args, 0, stream);
  }

  k_gemm<64, 64><<<(N + 15) / 16, 256, 0, stream>>>(x, W1, dinv, h1, N);
  k_prop64f<<<(N + 15) / 16, 256, 0, stream>>>((const __half2*)h1, rec, rowptr,
                                               dinv, b1, W2, h2, N);
  k_prop32<<<(N + 31) / 32, 256, 0, stream>>>((const __half2*)h2, rec, rowptr, dinv,
                                              b2, (float*)d_out, N);
}

// Round 16
// 121.858 us; speedup vs baseline: 2.6881x; 2.6881x over previous
//
#include <hip/hip_runtime.h>
#include <hip/hip_fp16.h>
#include <cstdint>
#include <cstddef>

// ---------------------------------------------------------------------------
// GCN 2-layer: out = GCNConv2( relu( GCNConv1(x) ) )
// Build — zero global atomics, 4 kernels (launches = global barriers):
//   k_histA    : per-chunk LDS histogram over 256-node buckets -> histM
//   k_colscanA : per-bucket scan over chunks (chunk offsets) + bucket totals
//   k_scatter  : per-block local scan of btot -> bbase (block 0 publishes);
//                direct scatter via LDS cursors into bucket-grouped raw[]
//   k_sort     : per-bucket node histogram + scan -> rowptr/dinv + LDS
//                counting sort -> per-node CSR rec[]; block 0 writes
//                zero-rows of h1/h2 and rowptr[N]
// Compute:
//   k_gemm    : Hs1(fp16) = (X @ W1) * dinv[row]
//   k_prop64f : FUSED layer-1 prop + layer-2 transform (g1 in regs/LDS,
//               matvec epilogue) -> h2(fp16) = (g1 @ W2) * dinv
//   k_prop32  : out[n] = dinv[n]*(sum h2[src] + h2[n]) + b2  (fp32 out)
// Edge dtype (int32 vs int64) detected per-block via wave-0 ballot on the
// odd 32-bit words of the first 64 edges (int64 node ids < 2^31 -> all 0).
// NOTE (r15 lesson): cooperative grid.sync() on this chip costs ~50 µs per
// sync (cross-XCD coherence spin) — kernel launches are the cheap barrier.
// ---------------------------------------------------------------------------

#define CHUNK 4096      // edges per partition block
#define BKN 256         // nodes per bucket
#define BKN_SHIFT 8
#define NCH_MAX 512     // max chunks / max buckets
#define SCAP2 5120      // LDS cap per bucket in sort (mean 4096, +16 sigma)

__device__ __forceinline__ int load_edge(const int* e32, int idx, int is64) {
  if (is64) return (int)((const long long*)e32)[idx];
  return e32[idx];
}

// wave-0 ballot over odd words of first 64 edges; result via LDS to all waves.
__device__ __forceinline__ int detect_is64_block(const int* e32, int* s_tmp) {
  const int t = threadIdx.x;
  if (t < 64) {
    int v = e32[2 * t + 1];
    unsigned long long b = __ballot(v != 0);
    if (t == 0) *s_tmp = (b == 0ULL);  // all-zero high words -> int64
  }
  __syncthreads();
  return *s_tmp;
}

// inclusive Hillis-Steele over 512 LDS slots with 256 threads
__device__ __forceinline__ void block_scan512(int* sh, int t) {
  for (int off = 1; off < 512; off <<= 1) {
    int i0 = t, i1 = t + 256;
    int v0 = sh[i0] + ((i0 >= off) ? sh[i0 - off] : 0);
    int v1 = sh[i1] + ((i1 >= off) ? sh[i1 - off] : 0);
    __syncthreads();
    sh[i0] = v0;
    sh[i1] = v1;
    __syncthreads();
  }
}

// ---- per-chunk bucket histogram (LDS atomics only, no global atomics) ----
__global__ void k_histA(const int* __restrict__ e32, int E, int* __restrict__ histM,
                        int NBUCK) {
  __shared__ int lh[NCH_MAX];
  __shared__ int s_is64;
  const int c = blockIdx.x;
  const int t = threadIdx.x;
  const int is64 = detect_is64_block(e32, &s_is64);
  for (int i = t; i < NBUCK; i += 256) lh[i] = 0;
  __syncthreads();
  const int beg = c * CHUNK;
  const int n = min(CHUNK, E - beg);
  for (int i = t; i < n; i += 256) {
    int d = load_edge(e32, E + beg + i, is64);
    atomicAdd(&lh[d >> BKN_SHIFT], 1);  // LDS atomic: on-CU, cheap
  }
  __syncthreads();
  for (int i = t; i < NBUCK; i += 256) histM[(size_t)c * NBUCK + i] = lh[i];
}

// ---- per-bucket scan over chunks: histM -> within-bucket chunk offsets ----
__global__ void k_colscanA(int* __restrict__ histM, int* __restrict__ btot,
                           int NCH, int NBUCK) {
  __shared__ int sh[NCH_MAX];
  const int b = blockIdx.x;
  const int t = threadIdx.x;
  for (int i = t; i < NCH_MAX; i += 256)
    sh[i] = (i < NCH) ? histM[(size_t)i * NBUCK + b] : 0;
  __syncthreads();
  block_scan512(sh, t);  // inclusive
  for (int i = t; i < NCH; i += 256)
    histM[(size_t)i * NBUCK + b] = (i == 0) ? 0 : sh[i - 1];  // exclusive, no base
  if (t == 0) btot[b] = sh[NCH_MAX - 1];  // bucket total (tail slots are zero)
}

// ---- scatter: per-block local scan of btot -> bases; LDS-cursor scatter ----
__global__ void k_scatter(const int* __restrict__ e32, int E, const int* __restrict__ histM,
                          const int* __restrict__ btot, int* __restrict__ bbase,
                          int NBUCK, unsigned int* __restrict__ raw) {
  __shared__ int sh[NCH_MAX];     // btot scan
  __shared__ int lcur[NCH_MAX];   // write cursors
  __shared__ int s_is64;
  const int c = blockIdx.x;
  const int t = threadIdx.x;
  const int is64 = detect_is64_block(e32, &s_is64);
  for (int i = t; i < NCH_MAX; i += 256) sh[i] = (i < NBUCK) ? btot[i] : 0;
  __syncthreads();
  block_scan512(sh, t);  // inclusive -> bbase[i] = sh[i-1]
  for (int i = t; i < NBUCK; i += 256)
    lcur[i] = ((i == 0) ? 0 : sh[i - 1]) + histM[(size_t)c * NBUCK + i];
  if (c == 0) {  // publish bbase for k_sort
    for (int i = t; i < NBUCK; i += 256) bbase[i] = (i == 0) ? 0 : sh[i - 1];
    if (t == 0) bbase[NBUCK] = E;
  }
  __syncthreads();
  const int beg = c * CHUNK;
  const int cnt = min(CHUNK, E - beg);
  for (int i = t; i < cnt; i += 256) {
    int s = load_edge(e32, beg + i, is64);
    int d = load_edge(e32, E + beg + i, is64);
    int pos = atomicAdd(&lcur[d >> BKN_SHIFT], 1);
    raw[pos] = ((unsigned int)(d & (BKN - 1)) << 23) | (unsigned int)s;
  }
}

// ---- per-bucket: node histogram + scan -> rowptr/dinv; counting sort -> rec ----
// Block 0 also writes the zero-rows of h1/h2 and rowptr[N].
__global__ void k_sort(const unsigned int* __restrict__ raw, const int* __restrict__ bbase,
                       int* __restrict__ rec, int* __restrict__ rowptr,
                       float* __restrict__ dinv, __half* __restrict__ h1,
                       __half* __restrict__ h2, int N) {
  __shared__ int srec[SCAP2];
  __shared__ int sh[BKN];
  const int b = blockIdx.x;
  const int t = threadIdx.x;
  if (b == 0) {
    if (t < 64) {
      h1[(size_t)N * 64 + t] = __float2half(0.f);   // zero-row (gather target)
      if (t < 32) h2[(size_t)N * 32 + t] = __float2half(0.f);
    }
    if (t == 0) rowptr[N] = bbase[N >> BKN_SHIFT == 0 ? 1 : ((N + BKN - 1) / BKN)];
  }
  const int nodebase = b << BKN_SHIFT;
  const int base = bbase[b];
  const int end = bbase[b + 1];
  const int count = end - base;
  sh[t] = 0;
  __syncthreads();
  for (int i = t; i < count; i += 256) atomicAdd(&sh[raw[base + i] >> 23], 1);
  __syncthreads();
  const int deg = sh[t];  // in-degree of node nodebase+t
  // inclusive scan of sh
  for (int off = 1; off < 256; off <<= 1) {
    int add = (t >= off) ? sh[t - off] : 0;
    __syncthreads();
    sh[t] += add;
    __syncthreads();
  }
  const int excl = sh[t] - deg;
  const int n = nodebase + t;
  if (n < N) {
    rowptr[n] = base + excl;                   // coalesced, atomic-free
    dinv[n] = rsqrtf((float)deg + 1.0f);       // +1 = self-loop
  }
  __syncthreads();
  sh[t] = excl;  // local cursors
  __syncthreads();
  if (count <= SCAP2) {
    for (int i = t; i < count; i += 256) {
      unsigned int r = raw[base + i];
      int pos = atomicAdd(&sh[r >> 23], 1);
      srec[pos] = (int)(r & 0x7FFFFFu);
    }
    __syncthreads();
    for (int i = t; i < count; i += 256) rec[base + i] = srec[i];
  } else {  // statistically unreachable fallback: direct global placement
    for (int i = t; i < count; i += 256) {
      unsigned int r = raw[base + i];
      int pos = atomicAdd(&sh[r >> 23], 1);
      rec[base + pos] = (int)(r & 0x7FFFFFu);
    }
  }
}

// ---- dense transform Hs[N][COUT] = (X[N][CIN] @ W) * dinv[row], fp16 out ----
template <int CIN, int COUT>
__global__ void k_gemm(const float* __restrict__ Xv, const float* __restrict__ W,
                       const float* __restrict__ dinv, __half* __restrict__ H, int N) {
  constexpr int Q = COUT / 4;
  constexpr int NODES = 256 / Q;
  __shared__ float4 Ws[CIN * Q];
  __shared__ float Xs[NODES][CIN + 1];
  const int t = threadIdx.x;
  const int nodebase = blockIdx.x * NODES;

  const float4* W4 = (const float4*)W;
#pragma unroll
  for (int i = t; i < CIN * Q; i += 256) Ws[i] = W4[i];

  const float4* X4 = (const float4*)Xv;
#pragma unroll
  for (int i = t; i < NODES * (CIN / 4); i += 256) {
    int r = i / (CIN / 4);
    int k4 = i % (CIN / 4);
    int gr = nodebase + r;
    if (gr > N - 1) gr = N - 1;
    float4 v = X4[(size_t)gr * (CIN / 4) + k4];
    Xs[r][k4 * 4 + 0] = v.x;
    Xs[r][k4 * 4 + 1] = v.y;
    Xs[r][k4 * 4 + 2] = v.z;
    Xs[r][k4 * 4 + 3] = v.w;
  }
  __syncthreads();

  const int q = t % Q;
  const int nl = t / Q;
  const int n = nodebase + nl;
  float4 acc = make_float4(0.f, 0.f, 0.f, 0.f);
#pragma unroll 4
  for (int k = 0; k < CIN; ++k) {
    float xv = Xs[nl][k];
    float4 wv = Ws[k * Q + q];
    acc.x = fmaf(xv, wv.x, acc.x);
    acc.y = fmaf(xv, wv.y, acc.y);
    acc.z = fmaf(xv, wv.z, acc.z);
    acc.w = fmaf(xv, wv.w, acc.w);
  }
  if (n < N) {
    float dn = dinv[n];  // fold symmetric norm into stored features
    __half2* H2 = (__half2*)H;
    H2[(size_t)n * (COUT / 2) + 2 * q + 0] = __floats2half2_rn(acc.x * dn, acc.y * dn);
    H2[(size_t)n * (COUT / 2) + 2 * q + 1] = __floats2half2_rn(acc.z * dn, acc.w * dn);
  }
}

// accumulate a float4 (= 8 fp16 channels) into 4 f32 float2 accumulators
__device__ __forceinline__ void acc_row(float4 hv, float2& a0, float2& a1,
                                        float2& a2, float2& a3) {
  union { float f; __half2 h; } c0, c1, c2, c3;
  c0.f = hv.x; c1.f = hv.y; c2.f = hv.z; c3.f = hv.w;
  float2 f0 = __half22float2(c0.h), f1 = __half22float2(c1.h);
  float2 f2 = __half22float2(c2.h), f3 = __half22float2(c3.h);
  a0.x += f0.x; a0.y += f0.y;
  a1.x += f1.x; a1.y += f1.y;
  a2.x += f2.x; a2.y += f2.y;
  a3.x += f3.x; a3.y += f3.y;
}

#define RED2(v, m) { v.x += __shfl_xor(v.x, m); v.y += __shfl_xor(v.y, m); }

// ---- FUSED layer-1 prop + layer-2 transform ----
// 4 nodes/wave, 2 groups x 8 lanes, unroll-8 stride-16 gather loop (MLP-8).
// Epilogue: g1 row (relu'd, f32) -> per-wave LDS; 16-lane matvec with W2
// pairs (broadcast LDS reads); h2[n] = (g1row @ W2) * dinv[n], fp16.
__global__ void k_prop64f(const __half2* __restrict__ H2, const int* __restrict__ rec,
                          const int* __restrict__ rowptr, const float* __restrict__ dinv,
                          const float* __restrict__ b1, const float* __restrict__ W2,
                          __half* __restrict__ h2, int N) {
  __shared__ float2 W2p[64 * 16];        // W2p[c][k] = (W2[c][k], W2[c][k+16])
  __shared__ float g1buf[4][4][68];      // [wave][node][64ch + pad]
  const int t = threadIdx.x;
  const int lane = t & 63;
  const int wave = t >> 6;
  // stage paired W2 (8 KB)
  for (int i = t; i < 64 * 16; i += 256) {
    int c = i >> 4, k = i & 15;
    W2p[i] = make_float2(W2[c * 32 + k], W2[c * 32 + 16 + k]);
  }

  const int nl = lane >> 4;                       // node within wave 0..3
  int n = blockIdx.x * 16 + wave * 4 + nl;
  if (n > N - 1) n = N - 1;                       // clamp (dup compute, benign)
  const int g = (lane & 15) >> 3;                 // edge group 0..1
  const int l8 = lane & 7;                        // float4 index (8 channels)
  const float di = dinv[n];
  const int beg = rowptr[n];
  const int end = rowptr[n + 1];
  const float4* H4 = (const float4*)H2;
  float2 a0 = {0.f, 0.f}, a1 = {0.f, 0.f}, a2 = {0.f, 0.f}, a3 = {0.f, 0.f};
  acc_row(H4[(size_t)(g == 0 ? n : N) * 8 + l8], a0, a1, a2, a3);  // self-loop
  for (int e = beg + g; e < end; e += 16) {
    // slot 0 guaranteed by loop condition; slots 1-7 gather zero-row on tail
    int s0 = rec[e];
    int s1 = (e + 2  < end) ? rec[e + 2]  : N;   // rec has +64 slack
    int s2 = (e + 4  < end) ? rec[e + 4]  : N;
    int s3 = (e + 6  < end) ? rec[e + 6]  : N;
    int s4 = (e + 8  < end) ? rec[e + 8]  : N;
    int s5 = (e + 10 < end) ? rec[e + 10] : N;
    int s6 = (e + 12 < end) ? rec[e + 12] : N;
    int s7 = (e + 14 < end) ? rec[e + 14] : N;
    acc_row(H4[(size_t)s0 * 8 + l8], a0, a1, a2, a3);
    acc_row(H4[(size_t)s1 * 8 + l8], a0, a1, a2, a3);
    acc_row(H4[(size_t)s2 * 8 + l8], a0, a1, a2, a3);
    acc_row(H4[(size_t)s3 * 8 + l8], a0, a1, a2, a3);
    acc_row(H4[(size_t)s4 * 8 + l8], a0, a1, a2, a3);
    acc_row(H4[(size_t)s5 * 8 + l8], a0, a1, a2, a3);
    acc_row(H4[(size_t)s6 * 8 + l8], a0, a1, a2, a3);
    acc_row(H4[(size_t)s7 * 8 + l8], a0, a1, a2, a3);
  }
  // combine the 2 groups (mask stays within the 16-lane span = one node);
  // after this BOTH groups hold the full sums.
  RED2(a0, 8)  RED2(a1, 8)  RED2(a2, 8)  RED2(a3, 8)

  // g1 row values: relu(a*di + b1), channels 8*l8..8*l8+7
  const float4* B4 = (const float4*)b1;
  float4 bb0 = B4[l8 * 2 + 0], bb1 = B4[l8 * 2 + 1];
  if (g == 0) {
    float4 r0 = make_float4(fmaxf(fmaf(a0.x, di, bb0.x), 0.f),
                            fmaxf(fmaf(a0.y, di, bb0.y), 0.f),
                            fmaxf(fmaf(a1.x, di, bb0.z), 0.f),
                            fmaxf(fmaf(a1.y, di, bb0.w), 0.f));
    float4 r1 = make_float4(fmaxf(fmaf(a2.x, di, bb1.x), 0.f),
                            fmaxf(fmaf(a2.y, di, bb1.y), 0.f),
                            fmaxf(fmaf(a3.x, di, bb1.z), 0.f),
                            fmaxf(fmaf(a3.y, di, bb1.w), 0.f));
    *(float4*)&g1buf[wave][nl][l8 * 8 + 0] = r0;
    *(float4*)&g1buf[wave][nl][l8 * 8 + 4] = r1;
  }
  __syncthreads();  // W2p staged AND g1buf written (all threads reach)

  // matvec: lane k in node span computes outputs k and k+16
  const int k = lane & 15;
  float o0 = 0.f, o1 = 0.f;
#pragma unroll
  for (int c4 = 0; c4 < 16; ++c4) {
    float4 r = *(const float4*)&g1buf[wave][nl][c4 * 4];  // broadcast read
    float2 w0 = W2p[(c4 * 4 + 0) * 16 + k];               // broadcast read
    float2 w1 = W2p[(c4 * 4 + 1) * 16 + k];
    float2 w2 = W2p[(c4 * 4 + 2) * 16 + k];
    float2 w3 = W2p[(c4 * 4 + 3) * 16 + k];
    o0 = fmaf(r.x, w0.x, o0); o1 = fmaf(r.x, w0.y, o1);
    o0 = fmaf(r.y, w1.x, o0); o1 = fmaf(r.y, w1.y, o1);
    o0 = fmaf(r.z, w2.x, o0); o1 = fmaf(r.z, w2.y, o1);
    o0 = fmaf(r.w, w3.x, o0); o1 = fmaf(r.w, w3.y, o1);
  }
  // h2[n][c'] = (g1 @ W2)[c'] * dinv[n]   (bias2 added in k_prop32)
  h2[(size_t)n * 32 + k]      = __float2half(o0 * di);
  h2[(size_t)n * 32 + k + 16] = __float2half(o1 * di);
}

// ---- pull prop C=32: 8 nodes/wave, 2 groups x 4 lanes, unroll-8 stride-16 ----
__global__ void k_prop32(const __half2* __restrict__ H2, const int* __restrict__ rec,
                         const int* __restrict__ rowptr, const float* __restrict__ dinv,
                         const float* __restrict__ bias, float* __restrict__ out, int N) {
  const int lane = threadIdx.x & 63;
  const int wave = threadIdx.x >> 6;
  const int n = blockIdx.x * 32 + wave * 8 + (lane >> 3);  // 32 nodes per block
  if (n >= N) return;
  const int g = (lane & 7) >> 2;   // edge group 0..1 within the 8-lane span
  const int l4 = lane & 3;         // float4 index within row (8 channels)
  const float di = dinv[n];
  const int beg = rowptr[n];
  const int end = rowptr[n + 1];
  const float4* H4 = (const float4*)H2;
  float2 a0 = {0.f, 0.f}, a1 = {0.f, 0.f}, a2 = {0.f, 0.f}, a3 = {0.f, 0.f};
  acc_row(H4[(size_t)(g == 0 ? n : N) * 4 + l4], a0, a1, a2, a3);  // self-loop
  for (int e = beg + g; e < end; e += 16) {
    int s0 = rec[e];
    int s1 = (e + 2  < end) ? rec[e + 2]  : N;
    int s2 = (e + 4  < end) ? rec[e + 4]  : N;
    int s3 = (e + 6  < end) ? rec[e + 6]  : N;
    int s4 = (e + 8  < end) ? rec[e + 8]  : N;
    int s5 = (e + 10 < end) ? rec[e + 10] : N;
    int s6 = (e + 12 < end) ? rec[e + 12] : N;
    int s7 = (e + 14 < end) ? rec[e + 14] : N;
    acc_row(H4[(size_t)s0 * 4 + l4], a0, a1, a2, a3);
    acc_row(H4[(size_t)s1 * 4 + l4], a0, a1, a2, a3);
    acc_row(H4[(size_t)s2 * 4 + l4], a0, a1, a2, a3);
    acc_row(H4[(size_t)s3 * 4 + l4], a0, a1, a2, a3);
    acc_row(H4[(size_t)s4 * 4 + l4], a0, a1, a2, a3);
    acc_row(H4[(size_t)s5 * 4 + l4], a0, a1, a2, a3);
    acc_row(H4[(size_t)s6 * 4 + l4], a0, a1, a2, a3);
    acc_row(H4[(size_t)s7 * 4 + l4], a0, a1, a2, a3);
  }
  // combine the 2 groups (mask stays within the 8-lane span = one node)
  RED2(a0, 4)  RED2(a1, 4)  RED2(a2, 4)  RED2(a3, 4)
  if (g) return;
  const float4* B4 = (const float4*)bias;
  float4 b0 = B4[l4 * 2 + 0], b1 = B4[l4 * 2 + 1];
  ((float4*)out)[(size_t)n * 8 + l4 * 2 + 0] =
      make_float4(fmaf(a0.x, di, b0.x), fmaf(a0.y, di, b0.y),
                  fmaf(a1.x, di, b0.z), fmaf(a1.y, di, b0.w));
  ((float4*)out)[(size_t)n * 8 + l4 * 2 + 1] =
      make_float4(fmaf(a2.x, di, b1.x), fmaf(a2.y, di, b1.y),
                  fmaf(a3.x, di, b1.z), fmaf(a3.y, di, b1.w));
}

extern "C" void kernel_launch(void* const* d_in, const int* in_sizes, int n_in,
                              void* d_out, int out_size, void* d_ws, size_t ws_size,
                              hipStream_t stream) {
  (void)n_in; (void)out_size; (void)ws_size;
  const float* x = (const float*)d_in[0];
  const int* edges = (const int*)d_in[1];
  const float* W1 = (const float*)d_in[2];
  const float* b1 = (const float*)d_in[3];
  const float* W2 = (const float*)d_in[4];
  const float* b2 = (const float*)d_in[5];

  const int N = in_sizes[0] / 64;
  const int E = in_sizes[1] / 2;
  const int NCH = (E + CHUNK - 1) / CHUNK;        // 391 (<= 512)
  const int NBUCK = (N + BKN - 1) / BKN;          // 391 (<= 512)

  // workspace carve-up (256B aligned)
  char* ws = (char*)d_ws;
  size_t off = 0;
  auto carve = [&](size_t bytes) -> void* {
    void* p = ws + off;
    off = (off + bytes + 255) & ~(size_t)255;
    return p;
  };
  int* rowptr        = (int*)carve((size_t)(N + 1) * 4);
  float* dinv        = (float*)carve((size_t)N * 4);
  int* btot          = (int*)carve((size_t)NBUCK * 4);
  int* bbase         = (int*)carve((size_t)(NBUCK + 1) * 4);
  int* histM         = (int*)carve((size_t)NCH * NBUCK * 4);
  unsigned int* raw  = (unsigned int*)carve((size_t)E * 4);
  int* rec           = (int*)carve(((size_t)E + 64) * 4);   // +slack for over-read
  __half* h1         = (__half*)carve((size_t)(N + 1) * 64 * 2);  // +zero-row
  __half* h2         = (__half*)carve((size_t)(N + 1) * 32 * 2);

  k_histA<<<NCH, 256, 0, stream>>>(edges, E, histM, NBUCK);
  k_colscanA<<<NBUCK, 256, 0, stream>>>(histM, btot, NCH, NBUCK);
  k_scatter<<<NCH, 256, 0, stream>>>(edges, E, histM, btot, bbase, NBUCK, raw);
  k_sort<<<NBUCK, 256, 0, stream>>>(raw, bbase, rec, rowptr, dinv, h1, h2, N);

  k_gemm<64, 64><<<(N + 15) / 16, 256, 0, stream>>>(x, W1, dinv, h1, N);
  k_prop64f<<<(N + 15) / 16, 256, 0, stream>>>((const __half2*)h1, rec, rowptr,
                                               dinv, b1, W2, h2, N);
  k_prop32<<<(N + 31) / 32, 256, 0, stream>>>((const __half2*)h2, rec, rowptr, dinv,
                                              b2, (float*)d_out, N);
}